// Round 8
// baseline (678.951 us; speedup 1.0000x reference)
//
#include <hip/hip_runtime.h>
#include <stdint.h>

#define HIDDEN 1024
#define BATCH  4
#define SEQ    2048
#define TOKENS (BATCH * SEQ)      // 8192
#define QKVD   (3 * HIDDEN)       // 3072

typedef unsigned short u16;
typedef __attribute__((ext_vector_type(8))) short   short8;   // 8 bf16 = 4 VGPRs
typedef __attribute__((ext_vector_type(4))) float   floatx4;

// deterministic round-to-nearest-even f32 -> bf16 (no NaN inputs here)
__device__ __forceinline__ u16 f32_bf16_rne(float f) {
    unsigned int u = __float_as_uint(f);
    u += 0x7FFFu + ((u >> 16) & 1u);
    return (u16)(u >> 16);
}

// LDS-only barrier: lgkmcnt(0)+s_barrier, NO vmcnt drain -> global loads stay
// in flight across it.
#define BAR() asm volatile("s_waitcnt lgkmcnt(0)\n\ts_barrier" ::: "memory")

// ---------------------------------------------------------------- convert
// both tensors (x then W) in one launch
__global__ __launch_bounds__(256) void cvt_bf16_kernel(
        const float* __restrict__ x, u16* __restrict__ xb,
        const float* __restrict__ w, u16* __restrict__ wb,
        int nx4, int nw4) {
    int i = blockIdx.x * 256 + threadIdx.x;
    const float* src; u16* dst;
    if (i < nx4) { src = x; dst = xb; }
    else { i -= nx4; if (i >= nw4) return; src = w; dst = wb; }
    float4 v = ((const float4*)src)[i];
    ushort4 o;
    o.x = f32_bf16_rne(v.x); o.y = f32_bf16_rne(v.y);
    o.z = f32_bf16_rne(v.z); o.w = f32_bf16_rne(v.w);
    ((ushort4*)dst)[i] = o;
}

// ---------------------------------------------------------------- GEMM wide (NT)
// C[M,N] = A[M,K]*B[N,K]^T. 128x256 block tile, BK=32, 4 waves, wave tile
// 64x128 (acc[8][4], 32 MFMA/wave-iter -> 2x MFMA per unit of serial staging
// overhead vs the 128x128 engine; rounds 1-6 showed occupancy pinned ~2
// blocks/CU regardless of caps, so per-wave MFMA density is the lever).
// Register-staged dbuf pipeline (round 6, 2-phase vmcnt distance).
// Unified LDS buffer: [A 8KB | B 16KB], chunk c (16 rows x 32k, swizzled) at
// c*512 elems; chunks 0..7 = A rows, 8..23 = B rows. Each wave stages 6.
// Verified swizzle (rounds 3-6: full coalescing, zero bank conflicts).
// EPI: 0 = bf16 store + bias[col]; 1 = f32 store * scale.
struct StageW { uint4 v[6]; };

template <int EPI>
__global__ __launch_bounds__(256, 2) void gemm_bt_wide(
        const u16* __restrict__ A, const u16* __restrict__ B,
        void* __restrict__ Cv, const float* __restrict__ bias,
        int K, int lda, int ldb, int ldc,
        size_t sA, size_t sB, size_t sC, float scale) {
    __shared__ u16 S0[12288], S1[12288];   // 24 KB each

    const int t    = threadIdx.x;
    const int lane = t & 63;
    const int wid  = t >> 6;
    const int bm   = blockIdx.y * 128;
    const int bn   = blockIdx.x * 256;

    const u16* Ab = A + (size_t)blockIdx.z * sA;
    const u16* Bb = B + (size_t)blockIdx.z * sB;

    const int srow = lane >> 2;
    const int scol = ((lane & 3) ^ ((lane >> 3) & 3)) * 8;

    const int wm = (wid >> 1) * 64;
    const int wn = (wid & 1) * 128;
    const int fr = lane & 15;
    const int fc = lane >> 4;
    const int foff = fr * 32 + ((fc ^ ((fr >> 1) & 3)) * 8);

    // 6 staging chunks per wave
    const u16* gp[6];
#pragma unroll
    for (int j = 0; j < 6; j++) {
        const int chunk = wid * 6 + j;
        gp[j] = (chunk < 8)
            ? Ab + (size_t)(bm + chunk * 16 + srow) * lda + scol
            : Bb + (size_t)(bn + (chunk - 8) * 16 + srow) * ldb + scol;
    }
    const int lbase = (wid * 6) * 512 + lane * 8;

    const int nk = K >> 5;

    auto ldst = [&](int kt) -> StageW {
        StageW s;
        const int off = kt << 5;
#pragma unroll
        for (int j = 0; j < 6; j++) s.v[j] = *(const uint4*)(gp[j] + off);
        return s;
    };
    auto wst = [&](u16* S_, const StageW& s) {
#pragma unroll
        for (int j = 0; j < 6; j++) *(uint4*)&S_[lbase + j * 512] = s.v[j];
    };

    floatx4 acc[8][4];
#pragma unroll
    for (int i = 0; i < 8; i++)
#pragma unroll
        for (int j = 0; j < 4; j++) acc[i][j] = (floatx4){0.f, 0.f, 0.f, 0.f};

    auto compute = [&](const u16* S_) {
        const u16* As_ = S_;                 // chunks 0..7
        const u16* Bs_ = S_ + 4096;          // chunks 8..23
        short8 af[4];
#pragma unroll
        for (int mi = 0; mi < 4; mi++)
            af[mi] = *(const short8*)&As_[((wm >> 4) + mi) * 512 + foff];
#pragma unroll
        for (int ni = 0; ni < 8; ni++) {
            short8 bf = *(const short8*)&Bs_[((wn >> 4) + ni) * 512 + foff];
#pragma unroll
            for (int mi = 0; mi < 4; mi++)
                acc[ni][mi] = __builtin_amdgcn_mfma_f32_16x16x32_bf16(
                    af[mi], bf, acc[ni][mi], 0, 0, 0);
        }
    };

    StageW ra = ldst(0);
    StageW rb = ldst(nk > 1 ? 1 : 0);
    wst(S0, ra);                             // precise vmcnt wait on ra only
    BAR();

    for (int kt = 0; kt < nk; kt += 2) {
        ra = ldst(kt + 2 < nk ? kt + 2 : nk - 1);
        compute(S0);
        wst(S1, rb);                         // rb issued 2 compute phases ago
        BAR();
        rb = ldst(kt + 3 < nk ? kt + 3 : nk - 1);
        compute(S1);
        wst(S0, ra);
        BAR();
    }

    // epilogue: C/D 16x16 mapping col=lane&15, row=(lane>>4)*4+reg
    const int crow0 = bm + wm + (lane >> 4) * 4;
    const int ccol0 = bn + wn + fr;
    const size_t coff = (size_t)blockIdx.z * sC;

    if (EPI == 0) {
        u16* C = (u16*)Cv;
#pragma unroll
        for (int ni = 0; ni < 8; ni++) {
            const float bv = bias[ccol0 + ni * 16];
#pragma unroll
            for (int mi = 0; mi < 4; mi++)
#pragma unroll
                for (int r = 0; r < 4; r++)
                    C[coff + (size_t)(crow0 + mi * 16 + r) * ldc + (ccol0 + ni * 16)] =
                        f32_bf16_rne(acc[ni][mi][r] + bv);
        }
    } else {
        float* C = (float*)Cv;
#pragma unroll
        for (int ni = 0; ni < 8; ni++)
#pragma unroll
            for (int mi = 0; mi < 4; mi++)
#pragma unroll
                for (int r = 0; r < 4; r++)
                    C[coff + (size_t)(crow0 + mi * 16 + r) * ldc + (ccol0 + ni * 16)] =
                        acc[ni][mi][r] * scale;
    }
}

// ---------------------------------------------------------------- GEMM 128x128
// round-6 register-staged engine, kept for PV (512 blocks; wider tile would
// drop grid below 1 block/CU). EPI: 2 = f32 store.
struct Stage { uint4 a0, a1, b0, b1; };

template <int EPI>
__global__ __launch_bounds__(256, 3) void gemm_bt(
        const u16* __restrict__ A, const u16* __restrict__ B,
        void* __restrict__ Cv, const float* __restrict__ bias,
        int K, int lda, int ldb, int ldc,
        size_t sA, size_t sB, size_t sC, float scale) {
    __shared__ u16 As0[4096], As1[4096];
    __shared__ u16 Bs0[4096], Bs1[4096];

    const int t    = threadIdx.x;
    const int lane = t & 63;
    const int wid  = t >> 6;
    const int bm   = blockIdx.y * 128;
    const int bn   = blockIdx.x * 128;

    const u16* Ab = A + (size_t)blockIdx.z * sA;
    const u16* Bb = B + (size_t)blockIdx.z * sB;

    const int srow = lane >> 2;
    const int scol = ((lane & 3) ^ ((lane >> 3) & 3)) * 8;

    const int wm = (wid >> 1) * 64;
    const int wn = (wid & 1) * 64;
    const int fr = lane & 15;
    const int fc = lane >> 4;
    const int foff = fr * 32 + ((fc ^ ((fr >> 1) & 3)) * 8);

    const int c0 = wid * 2, c1 = wid * 2 + 1;
    const u16* gA0 = Ab + (size_t)(bm + c0 * 16 + srow) * lda + scol;
    const u16* gA1 = Ab + (size_t)(bm + c1 * 16 + srow) * lda + scol;
    const u16* gB0 = Bb + (size_t)(bn + c0 * 16 + srow) * ldb + scol;
    const u16* gB1 = Bb + (size_t)(bn + c1 * 16 + srow) * ldb + scol;

    const int nk = K >> 5;

    auto ldst = [&](int kt) -> Stage {
        Stage s;
        const int off = kt << 5;
        s.a0 = *(const uint4*)(gA0 + off);
        s.a1 = *(const uint4*)(gA1 + off);
        s.b0 = *(const uint4*)(gB0 + off);
        s.b1 = *(const uint4*)(gB1 + off);
        return s;
    };
    auto wst = [&](u16* As_, u16* Bs_, const Stage& s) {
        *(uint4*)&As_[c0 * 512 + lane * 8] = s.a0;
        *(uint4*)&As_[c1 * 512 + lane * 8] = s.a1;
        *(uint4*)&Bs_[c0 * 512 + lane * 8] = s.b0;
        *(uint4*)&Bs_[c1 * 512 + lane * 8] = s.b1;
    };

    floatx4 acc[4][4];
#pragma unroll
    for (int i = 0; i < 4; i++)
#pragma unroll
        for (int j = 0; j < 4; j++) acc[i][j] = (floatx4){0.f, 0.f, 0.f, 0.f};

    auto compute = [&](const u16* As_, const u16* Bs_) {
        short8 bfr[4];
#pragma unroll
        for (int ni = 0; ni < 4; ni++)
            bfr[ni] = *(const short8*)&Bs_[((wn >> 4) + ni) * 512 + foff];
#pragma unroll
        for (int mi = 0; mi < 4; mi++) {
            short8 a = *(const short8*)&As_[((wm >> 4) + mi) * 512 + foff];
#pragma unroll
            for (int ni = 0; ni < 4; ni++)
                acc[mi][ni] = __builtin_amdgcn_mfma_f32_16x16x32_bf16(
                    a, bfr[ni], acc[mi][ni], 0, 0, 0);
        }
    };

    Stage ra = ldst(0);
    Stage rb = ldst(nk > 1 ? 1 : 0);
    wst(As0, Bs0, ra);
    BAR();

    for (int kt = 0; kt < nk; kt += 2) {
        ra = ldst(kt + 2 < nk ? kt + 2 : nk - 1);
        compute(As0, Bs0);
        wst(As1, Bs1, rb);
        BAR();
        rb = ldst(kt + 3 < nk ? kt + 3 : nk - 1);
        compute(As1, Bs1);
        wst(As0, Bs0, ra);
        BAR();
    }

    const int crow0 = bm + wm + (lane >> 4) * 4;
    const int ccol0 = bn + wn + fr;
    const size_t coff = (size_t)blockIdx.z * sC;

    float* C = (float*)Cv;
#pragma unroll
    for (int mi = 0; mi < 4; mi++)
#pragma unroll
        for (int ni = 0; ni < 4; ni++)
#pragma unroll
            for (int r = 0; r < 4; r++) {
                float v = acc[mi][ni][r];
                if (EPI == 1) v *= scale;
                C[coff + (size_t)(crow0 + mi * 16 + r) * ldc + (ccol0 + ni * 16)] = v;
            }
}

// ---------------------------------------------------------------- softmax
__global__ __launch_bounds__(256) void softmax_kernel(
        const float* __restrict__ S, u16* __restrict__ P) {
    __shared__ float redm[4];
    __shared__ float reds[4];
    const size_t base = (size_t)blockIdx.x * SEQ;
    const int t = threadIdx.x, lane = t & 63, wid = t >> 6;
    const float4* src = (const float4*)(S + base);
    float4 a = src[t], b = src[t + 256];

    float m = fmaxf(fmaxf(fmaxf(a.x, a.y), fmaxf(a.z, a.w)),
                    fmaxf(fmaxf(b.x, b.y), fmaxf(b.z, b.w)));
#pragma unroll
    for (int off = 32; off; off >>= 1) m = fmaxf(m, __shfl_xor(m, off, 64));
    if (lane == 0) redm[wid] = m;
    __syncthreads();
    m = fmaxf(fmaxf(redm[0], redm[1]), fmaxf(redm[2], redm[3]));

    float e[8];
    e[0] = __expf(a.x - m); e[1] = __expf(a.y - m);
    e[2] = __expf(a.z - m); e[3] = __expf(a.w - m);
    e[4] = __expf(b.x - m); e[5] = __expf(b.y - m);
    e[6] = __expf(b.z - m); e[7] = __expf(b.w - m);
    float s = e[0] + e[1] + e[2] + e[3] + e[4] + e[5] + e[6] + e[7];
#pragma unroll
    for (int off = 32; off; off >>= 1) s += __shfl_xor(s, off, 64);
    if (lane == 0) reds[wid] = s;
    __syncthreads();
    s = reds[0] + reds[1] + reds[2] + reds[3];
    const float r = 1.f / s;

    ushort4* dst = (ushort4*)(P + base);
    ushort4 o0, o1;
    o0.x = f32_bf16_rne(e[0] * r); o0.y = f32_bf16_rne(e[1] * r);
    o0.z = f32_bf16_rne(e[2] * r); o0.w = f32_bf16_rne(e[3] * r);
    o1.x = f32_bf16_rne(e[4] * r); o1.y = f32_bf16_rne(e[5] * r);
    o1.z = f32_bf16_rne(e[6] * r); o1.w = f32_bf16_rne(e[7] * r);
    dst[t] = o0;
    dst[t + 256] = o1;
}

// ---------------------------------------------------------------- V transpose
__global__ __launch_bounds__(256) void transposeV_kernel(
        const u16* __restrict__ qkv, u16* __restrict__ Vt) {
    __shared__ u16 tile[64][66];
    const int b = blockIdx.z;
    const int s0 = blockIdx.x * 64, h0 = blockIdx.y * 64;
    const int t = threadIdx.x;
    const int c = t & 63, r4 = t >> 6;
#pragma unroll
    for (int i = 0; i < 16; i++) {
        int sl = i * 4 + r4;
        tile[sl][c] = qkv[(size_t)(b * SEQ + s0 + sl) * QKVD + 2 * HIDDEN + h0 + c];
    }
    __syncthreads();
#pragma unroll
    for (int i = 0; i < 16; i++) {
        int hl = i * 4 + r4;
        Vt[(size_t)(b * HIDDEN + h0 + hl) * SEQ + s0 + c] = tile[c][hl];
    }
}

// ---------------------------------------------------------------- launch
extern "C" void kernel_launch(void* const* d_in, const int* in_sizes, int n_in,
                              void* d_out, int out_size, void* d_ws, size_t ws_size,
                              hipStream_t stream) {
    const float* x    = (const float*)d_in[0];
    const float* W    = (const float*)d_in[1];
    const float* bias = (const float*)d_in[2];
    float* out = (float*)d_out;

    u16* Xb  = (u16*)d_ws;                                  // 8192x1024 bf16
    u16* Wb  = Xb + (size_t)TOKENS * HIDDEN;                // 3072x1024 bf16
    u16* qkv = Wb + (size_t)QKVD * HIDDEN;                  // 8192x3072 bf16
    float* scores = (float*)(qkv + (size_t)TOKENS * QKVD);  // 4x2048x2048 f32
    u16* P  = (u16*)(scores + (size_t)BATCH * SEQ * SEQ);   // 4x2048x2048 bf16
    u16* Vt = P + (size_t)BATCH * SEQ * SEQ;                // 4x1024x2048 bf16

    // 1) fp32 -> bf16 casts (one launch)
    const int nx4 = TOKENS * HIDDEN / 4, nw4 = QKVD * HIDDEN / 4;
    cvt_bf16_kernel<<<(nx4 + nw4 + 255) / 256, 256, 0, stream>>>(x, Xb, W, Wb, nx4, nw4);

    // 2) QKV projection: qkv = Xb @ Wb^T + bias (bf16 out), 128x256 tiles
    gemm_bt_wide<0><<<dim3(QKVD / 256, TOKENS / 128, 1), 256, 0, stream>>>(
        Xb, Wb, qkv, bias, HIDDEN, HIDDEN, HIDDEN, QKVD, 0, 0, 0, 1.f);

    // 3) scores = scale * Q @ K^T per batch (f32 out), 128x256 tiles
    gemm_bt_wide<1><<<dim3(SEQ / 256, SEQ / 128, BATCH), 256, 0, stream>>>(
        qkv, qkv + HIDDEN, scores, nullptr, HIDDEN, QKVD, QKVD, SEQ,
        (size_t)SEQ * QKVD, (size_t)SEQ * QKVD, (size_t)SEQ * SEQ, 0.03125f);

    // 4) row softmax -> bf16 P
    softmax_kernel<<<BATCH * SEQ, 256, 0, stream>>>(scores, P);

    // 5) V transpose
    transposeV_kernel<<<dim3(SEQ / 64, HIDDEN / 64, BATCH), 256, 0, stream>>>(qkv, Vt);

    // 6) out = P @ Vt^T per batch (f32 out), 128x128 tiles
    gemm_bt<2><<<dim3(HIDDEN / 128, SEQ / 128, BATCH), 256, 0, stream>>>(
        P, Vt, out, nullptr, SEQ, SEQ, SEQ, HIDDEN,
        (size_t)SEQ * SEQ, (size_t)HIDDEN * SEQ, (size_t)SEQ * HIDDEN, 1.f);
}

// Round 9
// 378.751 us; speedup vs baseline: 1.7926x; 1.7926x over previous
//
#include <hip/hip_runtime.h>
#include <stdint.h>

#define HIDDEN 1024
#define BATCH  4
#define SEQ    2048
#define TOKENS (BATCH * SEQ)      // 8192
#define QKVD   (3 * HIDDEN)       // 3072

typedef unsigned short u16;
typedef __attribute__((ext_vector_type(8))) short   short8;   // 8 bf16 = 4 VGPRs
typedef __attribute__((ext_vector_type(4))) float   floatx4;

// deterministic round-to-nearest-even f32 -> bf16 (no NaN inputs here)
__device__ __forceinline__ u16 f32_bf16_rne(float f) {
    unsigned int u = __float_as_uint(f);
    u += 0x7FFFu + ((u >> 16) & 1u);
    return (u16)(u >> 16);
}

// LDS-only barrier: lgkmcnt(0)+s_barrier, NO vmcnt drain -> global loads stay
// in flight across it. Correct here: the only LDS producer (ds_write of B)
// is ordered by lgkmcnt; A never touches LDS.
#define BAR() asm volatile("s_waitcnt lgkmcnt(0)\n\ts_barrier" ::: "memory")

// ---------------------------------------------------------------- convert
__global__ __launch_bounds__(256) void cvt_bf16_kernel(
        const float* __restrict__ x, u16* __restrict__ xb,
        const float* __restrict__ w, u16* __restrict__ wb,
        int nx4, int nw4) {
    int i = blockIdx.x * 256 + threadIdx.x;
    const float* src; u16* dst;
    if (i < nx4) { src = x; dst = xb; }
    else { i -= nx4; if (i >= nw4) return; src = w; dst = wb; }
    float4 v = ((const float4*)src)[i];
    ushort4 o;
    o.x = f32_bf16_rne(v.x); o.y = f32_bf16_rne(v.y);
    o.z = f32_bf16_rne(v.z); o.w = f32_bf16_rne(v.w);
    ((ushort4*)dst)[i] = o;
}

// ---------------------------------------------------------------- GEMM (NT)
// C[M,N] = A[M,K]*B[N,K]^T. 128x128 tile, BK=32, 4 waves, wave 64x64 as 4x4
// of 16x16x32 bf16 MFMA.
//
// Round 9 structure: A-DIRECT. R6's engine was LDS-bound (48 KB LDS traffic
// per block-iter = 380-570 cyc vs MFMA 310). A fragments now load straight
// from global into registers in MFMA A-operand layout (row=bm+wm+mi*16+
// (lane&15), k=(lane>>4)*8 — 16x64B segments/instr, coalesced; duplicate
// read by the 2nd wave of each pair hits L1). Only B goes through LDS
// (register-staged dbuf, R6 pipeline, verified swizzle: 0 conflicts).
// LDS traffic halves to 24 KB/block-iter; LDS footprint 16 KB.
// R8's 64x128 wave tile spilled (1.18 GB scratch) — stay 64x64.
//
// EPI: 0 = bf16 store + bias[col]; 1 = f32 store * scale; 2 = f32 store.
struct StageB { uint4 b0, b1; };

template <int EPI>
__global__ __launch_bounds__(256, 3) void gemm_adirect(
        const u16* __restrict__ A, const u16* __restrict__ B,
        void* __restrict__ Cv, const float* __restrict__ bias,
        int K, int lda, int ldb, int ldc,
        size_t sA, size_t sB, size_t sC, float scale) {
    __shared__ u16 Bs0[4096], Bs1[4096];   // 8 KB each

    const int t    = threadIdx.x;
    const int lane = t & 63;
    const int wid  = t >> 6;
    const int bm   = blockIdx.y * 128;
    const int bn   = blockIdx.x * 128;

    const u16* Ab = A + (size_t)blockIdx.z * sA;
    const u16* Bb = B + (size_t)blockIdx.z * sB;

    // B staging geometry (verified R3-R6: full coalescing, 0 conflicts)
    const int srow = lane >> 2;
    const int scol = ((lane & 3) ^ ((lane >> 3) & 3)) * 8;
    const int c0 = wid * 2, c1 = wid * 2 + 1;
    const u16* gB0 = Bb + (size_t)(bn + c0 * 16 + srow) * ldb + scol;
    const u16* gB1 = Bb + (size_t)(bn + c1 * 16 + srow) * ldb + scol;

    // fragment geometry (verified m89/m91 mappings)
    const int wm = (wid >> 1) * 64;
    const int wn = (wid & 1) * 64;
    const int fr = lane & 15;
    const int fc = lane >> 4;
    const int fk = fc * 8;
    const int foff = fr * 32 + ((fc ^ ((fr >> 1) & 3)) * 8);

    // A-direct fragment pointers: lane reads its own 16B MFMA A-operand
    const u16* gA[4];
#pragma unroll
    for (int mi = 0; mi < 4; mi++)
        gA[mi] = Ab + (size_t)(bm + wm + mi * 16 + fr) * lda + fk;

    const int nk = K >> 5;

    auto ldB = [&](int kt) -> StageB {
        StageB s;
        const int off = kt << 5;
        s.b0 = *(const uint4*)(gB0 + off);
        s.b1 = *(const uint4*)(gB1 + off);
        return s;
    };
    auto wstB = [&](u16* Bs_, const StageB& s) {
        *(uint4*)&Bs_[c0 * 512 + lane * 8] = s.b0;
        *(uint4*)&Bs_[c1 * 512 + lane * 8] = s.b1;
    };
    struct AFrag { short8 f[4]; };
    auto ldA = [&](int kt) -> AFrag {
        AFrag a;
        const int off = kt << 5;
#pragma unroll
        for (int mi = 0; mi < 4; mi++)
            a.f[mi] = *(const short8*)(gA[mi] + off);
        return a;
    };

    floatx4 acc[4][4];
#pragma unroll
    for (int i = 0; i < 4; i++)
#pragma unroll
        for (int j = 0; j < 4; j++) acc[i][j] = (floatx4){0.f, 0.f, 0.f, 0.f};

    auto compute = [&](const u16* Bs_, const AFrag& a) {
        short8 bfr[4];
#pragma unroll
        for (int ni = 0; ni < 4; ni++)
            bfr[ni] = *(const short8*)&Bs_[((wn >> 4) + ni) * 512 + foff];
#pragma unroll
        for (int mi = 0; mi < 4; mi++)
#pragma unroll
            for (int ni = 0; ni < 4; ni++)
                acc[mi][ni] = __builtin_amdgcn_mfma_f32_16x16x32_bf16(
                    a.f[mi], bfr[ni], acc[mi][ni], 0, 0, 0);
    };

    // prologue: B(0) -> Bs0; B(1) in regs; A(0) in regs
    StageB rb = ldB(0);
    wstB(Bs0, rb);                      // precise vmcnt wait on rb only
    rb = ldB(nk > 1 ? 1 : 0);
    AFrag fa = ldA(0);
    BAR();

    for (int kt = 0; kt < nk; kt += 2) {
        // even: B tile kt in Bs0, A tile kt in fa
        AFrag fa2 = ldA(kt + 1 < nk ? kt + 1 : 0);
        compute(Bs0, fa);               // fa loads issued one iter ago
        wstB(Bs1, rb);                  // rb loads issued one iter ago
        rb = ldB(kt + 2 < nk ? kt + 2 : 0);
        BAR();
        // odd: B tile kt+1 in Bs1, A tile kt+1 in fa2
        fa = ldA(kt + 2 < nk ? kt + 2 : 0);
        compute(Bs1, fa2);
        wstB(Bs0, rb);
        rb = ldB(kt + 3 < nk ? kt + 3 : 0);
        BAR();
    }

    // epilogue: C/D 16x16 mapping col=lane&15, row=(lane>>4)*4+reg
    const int crow0 = bm + wm + (lane >> 4) * 4;
    const int ccol0 = bn + wn + fr;
    const size_t coff = (size_t)blockIdx.z * sC;

    if (EPI == 0) {
        u16* C = (u16*)Cv;
#pragma unroll
        for (int ni = 0; ni < 4; ni++) {
            const float bv = bias[ccol0 + ni * 16];
#pragma unroll
            for (int mi = 0; mi < 4; mi++)
#pragma unroll
                for (int r = 0; r < 4; r++)
                    C[coff + (size_t)(crow0 + mi * 16 + r) * ldc + (ccol0 + ni * 16)] =
                        f32_bf16_rne(acc[mi][ni][r] + bv);
        }
    } else {
        float* C = (float*)Cv;
#pragma unroll
        for (int mi = 0; mi < 4; mi++)
#pragma unroll
            for (int ni = 0; ni < 4; ni++)
#pragma unroll
                for (int r = 0; r < 4; r++) {
                    float v = acc[mi][ni][r];
                    if (EPI == 1) v *= scale;
                    C[coff + (size_t)(crow0 + mi * 16 + r) * ldc + (ccol0 + ni * 16)] = v;
                }
    }
}

// ---------------------------------------------------------------- softmax
__global__ __launch_bounds__(256) void softmax_kernel(
        const float* __restrict__ S, u16* __restrict__ P) {
    __shared__ float redm[4];
    __shared__ float reds[4];
    const size_t base = (size_t)blockIdx.x * SEQ;
    const int t = threadIdx.x, lane = t & 63, wid = t >> 6;
    const float4* src = (const float4*)(S + base);
    float4 a = src[t], b = src[t + 256];

    float m = fmaxf(fmaxf(fmaxf(a.x, a.y), fmaxf(a.z, a.w)),
                    fmaxf(fmaxf(b.x, b.y), fmaxf(b.z, b.w)));
#pragma unroll
    for (int off = 32; off; off >>= 1) m = fmaxf(m, __shfl_xor(m, off, 64));
    if (lane == 0) redm[wid] = m;
    __syncthreads();
    m = fmaxf(fmaxf(redm[0], redm[1]), fmaxf(redm[2], redm[3]));

    float e[8];
    e[0] = __expf(a.x - m); e[1] = __expf(a.y - m);
    e[2] = __expf(a.z - m); e[3] = __expf(a.w - m);
    e[4] = __expf(b.x - m); e[5] = __expf(b.y - m);
    e[6] = __expf(b.z - m); e[7] = __expf(b.w - m);
    float s = e[0] + e[1] + e[2] + e[3] + e[4] + e[5] + e[6] + e[7];
#pragma unroll
    for (int off = 32; off; off >>= 1) s += __shfl_xor(s, off, 64);
    if (lane == 0) reds[wid] = s;
    __syncthreads();
    s = reds[0] + reds[1] + reds[2] + reds[3];
    const float r = 1.f / s;

    ushort4* dst = (ushort4*)(P + base);
    ushort4 o0, o1;
    o0.x = f32_bf16_rne(e[0] * r); o0.y = f32_bf16_rne(e[1] * r);
    o0.z = f32_bf16_rne(e[2] * r); o0.w = f32_bf16_rne(e[3] * r);
    o1.x = f32_bf16_rne(e[4] * r); o1.y = f32_bf16_rne(e[5] * r);
    o1.z = f32_bf16_rne(e[6] * r); o1.w = f32_bf16_rne(e[7] * r);
    dst[t] = o0;
    dst[t + 256] = o1;
}

// ---------------------------------------------------------------- V transpose
__global__ __launch_bounds__(256) void transposeV_kernel(
        const u16* __restrict__ qkv, u16* __restrict__ Vt) {
    __shared__ u16 tile[64][66];
    const int b = blockIdx.z;
    const int s0 = blockIdx.x * 64, h0 = blockIdx.y * 64;
    const int t = threadIdx.x;
    const int c = t & 63, r4 = t >> 6;
#pragma unroll
    for (int i = 0; i < 16; i++) {
        int sl = i * 4 + r4;
        tile[sl][c] = qkv[(size_t)(b * SEQ + s0 + sl) * QKVD + 2 * HIDDEN + h0 + c];
    }
    __syncthreads();
#pragma unroll
    for (int i = 0; i < 16; i++) {
        int hl = i * 4 + r4;
        Vt[(size_t)(b * HIDDEN + h0 + hl) * SEQ + s0 + c] = tile[c][hl];
    }
}

// ---------------------------------------------------------------- launch
extern "C" void kernel_launch(void* const* d_in, const int* in_sizes, int n_in,
                              void* d_out, int out_size, void* d_ws, size_t ws_size,
                              hipStream_t stream) {
    const float* x    = (const float*)d_in[0];
    const float* W    = (const float*)d_in[1];
    const float* bias = (const float*)d_in[2];
    float* out = (float*)d_out;

    u16* Xb  = (u16*)d_ws;                                  // 8192x1024 bf16
    u16* Wb  = Xb + (size_t)TOKENS * HIDDEN;                // 3072x1024 bf16
    u16* qkv = Wb + (size_t)QKVD * HIDDEN;                  // 8192x3072 bf16
    float* scores = (float*)(qkv + (size_t)TOKENS * QKVD);  // 4x2048x2048 f32
    u16* P  = (u16*)(scores + (size_t)BATCH * SEQ * SEQ);   // 4x2048x2048 bf16
    u16* Vt = P + (size_t)BATCH * SEQ * SEQ;                // 4x1024x2048 bf16

    // 1) fp32 -> bf16 casts (one launch)
    const int nx4 = TOKENS * HIDDEN / 4, nw4 = QKVD * HIDDEN / 4;
    cvt_bf16_kernel<<<(nx4 + nw4 + 255) / 256, 256, 0, stream>>>(x, Xb, W, Wb, nx4, nw4);

    // 2) QKV projection: qkv = Xb @ Wb^T + bias (bf16 out)
    gemm_adirect<0><<<dim3(QKVD / 128, TOKENS / 128, 1), 256, 0, stream>>>(
        Xb, Wb, qkv, bias, HIDDEN, HIDDEN, HIDDEN, QKVD, 0, 0, 0, 1.f);

    // 3) scores = scale * Q @ K^T per batch (f32 out)
    gemm_adirect<1><<<dim3(SEQ / 128, SEQ / 128, BATCH), 256, 0, stream>>>(
        qkv, qkv + HIDDEN, scores, nullptr, HIDDEN, QKVD, QKVD, SEQ,
        (size_t)SEQ * QKVD, (size_t)SEQ * QKVD, (size_t)SEQ * SEQ, 0.03125f);

    // 4) row softmax -> bf16 P
    softmax_kernel<<<BATCH * SEQ, 256, 0, stream>>>(scores, P);

    // 5) V transpose
    transposeV_kernel<<<dim3(SEQ / 64, HIDDEN / 64, BATCH), 256, 0, stream>>>(qkv, Vt);

    // 6) out = P @ Vt^T per batch (f32 out)
    gemm_adirect<2><<<dim3(HIDDEN / 128, SEQ / 128, BATCH), 256, 0, stream>>>(
        P, Vt, out, nullptr, SEQ, SEQ, SEQ, HIDDEN,
        (size_t)SEQ * SEQ, (size_t)HIDDEN * SEQ, (size_t)SEQ * HIDDEN, 1.f);
}